// Round 7
// baseline (650.241 us; speedup 1.0000x reference)
//
#include <hip/hip_runtime.h>
#include <hip/hip_bf16.h>
#include <cstdint>
#include <cstddef>

// Problem constants
#define K_DIM   4096          // INF
#define N_DIM   11008         // OUTF
#define M_DIM   4096          // 2*2048
#define GROUPS  32
#define QROWS   512           // INF*4/32

typedef __bf16 bf16x8 __attribute__((ext_vector_type(8)));
typedef float  f32x4  __attribute__((ext_vector_type(4)));

// ---------------------------------------------------------------------------
// async 16B global -> LDS (wave-uniform LDS base + lane*16 semantics)
// ---------------------------------------------------------------------------
__device__ __forceinline__ void async16(const void* g, void* lds) {
    __builtin_amdgcn_global_load_lds(
        (const __attribute__((address_space(1))) uint32_t*)g,
        (__attribute__((address_space(3))) uint32_t*)lds,
        16, 0, 0);
}

#define FENCE() asm volatile("" ::: "memory")
#define BAR()   do { FENCE(); __builtin_amdgcn_s_barrier(); FENCE(); } while (0)

// ---------------------------------------------------------------------------
// Kernel 1: scales/zeros transpose+interleave:
//   szT[g][n>>2][0..3] = scales[n..n+3][g],  szT[g][n>>2][4..7] = zeros[...]
// One float8 (32 B) per 4-n group per g — the GEMM loads it as 2x float4.
// ---------------------------------------------------------------------------
__global__ __launch_bounds__(256) void szt_kernel(
        const float* __restrict__ s, const float* __restrict__ z,
        float* __restrict__ szT) {
    const int n = blockIdx.x * 256 + threadIdx.x;   // 0..11007
    const int g = blockIdx.y;                       // 0..31
    const size_t o = ((size_t)g * (N_DIM / 4) + (n >> 2)) * 8 + (n & 3);
    szT[o]     = s[(size_t)n * GROUPS + g];
    szT[o + 4] = z[(size_t)n * GROUPS + g];
}

// ---------------------------------------------------------------------------
// Kernel 2: x fp32 -> bf16 (RNE), 8 elements per thread (unchanged)
// ---------------------------------------------------------------------------
__global__ __launch_bounds__(256) void xconv_kernel(
        const float* __restrict__ x, __bf16* __restrict__ xb) {
    const size_t i = ((size_t)blockIdx.x * 256 + threadIdx.x) * 8;
    const float4* p = (const float4*)(x + i);
    float4 a = p[0];
    float4 b = p[1];
    bf16x8 o;
    o[0] = (__bf16)a.x; o[1] = (__bf16)a.y; o[2] = (__bf16)a.z; o[3] = (__bf16)a.w;
    o[4] = (__bf16)b.x; o[5] = (__bf16)b.y; o[6] = (__bf16)b.z; o[7] = (__bf16)b.w;
    *(bf16x8*)(xb + i) = o;
}

// ---------------------------------------------------------------------------
// Kernel 3: fused dequant + bf16 GEMM.  C = A(MxK) * W^T + bias, fp32 out,
// where W[k][n] = ((qw[k>>3][n] >> (4*(k&7))) & 0xF) * s[n][k>>7] - z[n][k>>7].
//
// 256x256 tile, BK=64, 512 threads = 8 waves (2M x 4N), acc[8][4] f32x4.
// A: staged bf16 via global_load_lds (pre-swizzled source, rule 21).
// B: staged QUANTIZED — per K-tile each thread loads ONE uint4 of qweight
//    (8 KB/tile vs 32 KB bf16: 4x less B traffic), dequants 32 values in
//    VALU (hides under MFMA via cross-wave co-issue, m114), ds_write_b128
//    into the SAME XOR-8 swizzled LDS layout the read side already uses.
//    One scale-group per K-tile (g = t>>1 since GROUPSIZE=128).
//
// R6 fix (R5 failed absmax=15): scale-group pointer must advance BETWEEN
// the two kgroups of a pair.  Staged tile 2gg+1 needs g=gg (first kgroup,
// then ADV), staged tile 2gg+2 needs g=gg+1 (second kgroup).  R5 had ADV
// on the second kgroup, so every even tile >=2 used group g-1.
//
// Sync: ONE barrier per K-tile (R3): seam = lgkm(0) [own ds_writes/reads]
// + vmcnt(0) [own A-stagings, aged ~1 tile] + BAR.
// ---------------------------------------------------------------------------
#define BM 256
#define BN 256
#define BK 64
#define NT 43            // N_DIM/256
#define MT 16            // M_DIM/256
#define NWG (NT*MT)      // 688 = 8*86 -> bijective XCD swizzle

#define MFMA4(AV, R)                                                          \
    acc[(R)][0] = __builtin_amdgcn_mfma_f32_16x16x32_bf16((AV), b0, acc[(R)][0], 0,0,0); \
    acc[(R)][1] = __builtin_amdgcn_mfma_f32_16x16x32_bf16((AV), b1, acc[(R)][1], 0,0,0); \
    acc[(R)][2] = __builtin_amdgcn_mfma_f32_16x16x32_bf16((AV), b2, acc[(R)][2], 0,0,0); \
    acc[(R)][3] = __builtin_amdgcn_mfma_f32_16x16x32_bf16((AV), b3, acc[(R)][3], 0,0,0);

// Dequant one thread's uint4 (4 n-columns x 8 k-nibbles) and write 4 x b128
// into the swizzled B tile at LDS offset (32768 + soff).
// Expression matches the reference dequant exactly (absmax-invariant).
#define DQ_WRITE(QV, SV, ZV, SOFF)                                            \
    do {                                                                      \
        const uint32_t qa_[4] = { (QV).x, (QV).y, (QV).z, (QV).w };           \
        const float    sa_[4] = { (SV).x, (SV).y, (SV).z, (SV).w };           \
        const float    za_[4] = { (ZV).x, (ZV).y, (ZV).z, (ZV).w };           \
        _Pragma("unroll")                                                     \
        for (int j = 0; j < 4; ++j) {                                         \
            const uint32_t qv = qa_[j];                                       \
            const float sj = sa_[j], zj = za_[j];                             \
            bf16x8 w;                                                         \
            _Pragma("unroll")                                                 \
            for (int i = 0; i < 8; ++i)                                       \
                w[i] = (__bf16)((float)((qv >> (4 * i)) & 0xFu) * sj - zj);   \
            const int r_ = (ng << 2) + j;                                     \
            *(bf16x8*)(lds + 32768 + (SOFF) + r_ * 64 +                       \
                       ((kkl ^ (r_ & 7)) << 3)) = w;                          \
        }                                                                     \
    } while (0)

// One K-tile (4 ks-major phases, ONE barrier).  STAGE: stage tile t+1
// (A async16 + q/sz reg loads at P0, dequant+ds_write at P2).  ADV: bump
// the sz pointer AFTER this kgroup's staging read (g advances when the
// NEXT staged tile crosses a 128-k group boundary).
template<bool STAGE, bool ADV>
__device__ __forceinline__ void kgroup(
        const __bf16* __restrict__ ar0, const __bf16* __restrict__ ar1,
        const __bf16* __restrict__ br0, const __bf16* __restrict__ br1,
        const __bf16* (&gsrcA)[4], __bf16* lds, const int (&ldstA)[4],
        const uint32_t*& qwp, const float*& szp,
        const int soff, f32x4 (&acc)[8][4])
{
    const int tid = threadIdx.x;
    const int kkl = tid & 7;
    const int ng  = tid >> 3;
    bf16x8 a0, a1, a2, a3, b0, b1, b2, b3;
    uint4 qf; float4 sf, zf;

    // ---- tile seam: publish tile t (stagings + dequant writes) ----
    asm volatile("s_waitcnt lgkmcnt(0)" ::: "memory");
    asm volatile("s_waitcnt vmcnt(0)" ::: "memory");
    BAR();

    // ---- p0 : ks0, mf0-3 ; issue tile-(t+1) staging ----
    if constexpr (STAGE) {
        async16(gsrcA[0], lds + ldstA[0] + soff);
        async16(gsrcA[1], lds + ldstA[1] + soff);
        async16(gsrcA[2], lds + ldstA[2] + soff);
        async16(gsrcA[3], lds + ldstA[3] + soff);
        qf = *(const uint4*)qwp;                    // B quant words, tile t+1
        sf = *(const float4*)szp;                   // scales (4 n-cols)
        zf = *(const float4*)(szp + 4);             // zeros
    }
    a0 = *(const bf16x8*)(ar0 + 0*1024);
    a1 = *(const bf16x8*)(ar0 + 1*1024);
    a2 = *(const bf16x8*)(ar0 + 2*1024);
    a3 = *(const bf16x8*)(ar0 + 3*1024);
    b0 = *(const bf16x8*)(br0 + 0*1024);
    b1 = *(const bf16x8*)(br0 + 1*1024);
    b2 = *(const bf16x8*)(br0 + 2*1024);
    b3 = *(const bf16x8*)(br0 + 3*1024);
    __builtin_amdgcn_s_setprio(1);
    MFMA4(a0, 0) MFMA4(a1, 1) MFMA4(a2, 2) MFMA4(a3, 3)
    __builtin_amdgcn_s_setprio(0);

    // ---- p1 : ks0, mf4-7 ----
    a0 = *(const bf16x8*)(ar0 + 4*1024);
    a1 = *(const bf16x8*)(ar0 + 5*1024);
    a2 = *(const bf16x8*)(ar0 + 6*1024);
    a3 = *(const bf16x8*)(ar0 + 7*1024);
    __builtin_amdgcn_s_setprio(1);
    MFMA4(a0, 4) MFMA4(a1, 5) MFMA4(a2, 6) MFMA4(a3, 7)
    __builtin_amdgcn_s_setprio(0);

    // ---- p2 : ks1, mf0-3 ; dequant B(t+1) -> other buffer ----
    a0 = *(const bf16x8*)(ar1 + 0*1024);
    a1 = *(const bf16x8*)(ar1 + 1*1024);
    a2 = *(const bf16x8*)(ar1 + 2*1024);
    a3 = *(const bf16x8*)(ar1 + 3*1024);
    b0 = *(const bf16x8*)(br1 + 0*1024);
    b1 = *(const bf16x8*)(br1 + 1*1024);
    b2 = *(const bf16x8*)(br1 + 2*1024);
    b3 = *(const bf16x8*)(br1 + 3*1024);
    if constexpr (STAGE) {
        DQ_WRITE(qf, sf, zf, soff);
    }
    __builtin_amdgcn_s_setprio(1);
    MFMA4(a0, 0) MFMA4(a1, 1) MFMA4(a2, 2) MFMA4(a3, 3)
    __builtin_amdgcn_s_setprio(0);

    // ---- p3 : ks1, mf4-7 ----
    a0 = *(const bf16x8*)(ar1 + 4*1024);
    a1 = *(const bf16x8*)(ar1 + 5*1024);
    a2 = *(const bf16x8*)(ar1 + 6*1024);
    a3 = *(const bf16x8*)(ar1 + 7*1024);
    __builtin_amdgcn_s_setprio(1);
    MFMA4(a0, 4) MFMA4(a1, 5) MFMA4(a2, 6) MFMA4(a3, 7)
    __builtin_amdgcn_s_setprio(0);

    if constexpr (STAGE) {
#pragma unroll
        for (int j = 0; j < 4; ++j) gsrcA[j] += BK;
        qwp += 8 * N_DIM;                       // next K-tile's qword rows
        if constexpr (ADV) szp += 2 * N_DIM;    // next scale group (g+1)
    }
}

__global__ __launch_bounds__(512, 2) void gemm_kernel(
        const __bf16* __restrict__ A,      // M x K row-major (bf16 x)
        const uint32_t* __restrict__ qw,   // QROWS x N packed 4-bit
        const float* __restrict__ szT,     // interleaved scales/zeros table
        const float* __restrict__ bias,    // N
        float* __restrict__ C) {           // M x N row-major
    __shared__ __align__(16) __bf16 lds[65536];   // 128 KiB

    const int tid  = threadIdx.x;
    const int wave = tid >> 6;
    const int lane = tid & 63;
    const int wm   = wave >> 2;      // 0..1
    const int wn   = wave & 3;       // 0..3
    const int quad = lane >> 4;      // 0..3
    const int l16  = lane & 15;

    // bijective XCD swizzle (688 % 8 == 0), m inner for B-panel L2 reuse
    const int bid = blockIdx.x;
    const int swz = (bid & 7) * (NWG / 8) + (bid >> 3);
    const int n_t = swz >> 4;        // 0..42
    const int m_t = swz & 15;        // 0..15
    const int m0 = m_t << 8;
    const int n0 = n_t << 8;

    f32x4 acc[8][4] = {};

    // ---- A staging source (pre-swizzled global addresses, rule 21) ----
    const int srow = tid >> 3;                       // 0..63 row within quarter
    const int scol = ((tid & 7) ^ (srow & 7)) << 3;  // swizzled k-chunk * 8

    const __bf16* gsrcA[4];
#pragma unroll
    for (int q = 0; q < 4; ++q)
        gsrcA[q] = A + (size_t)(m0 + q * 64 + srow) * K_DIM + scol;

    // wave-uniform LDS A dests (elements): quarter base + wave*512
    const int wq = wave << 9;
    const int ldstA[4] = { 0*4096 + wq, 1*4096 + wq, 2*4096 + wq, 3*4096 + wq };

    // ---- B quant-staging pointers ----
    const int kkl = tid & 7;                         // qword row within tile
    const int ng  = tid >> 3;                        // 4-n group 0..63
    const uint32_t* qwp = qw + (size_t)kkl * N_DIM + n0 + (ng << 2);
    const float*    szp = szT + ((size_t)(n0 >> 2) + ng) * 8;   // g=0

    // ---- prologue: tile 0 -> buf0 (A async16 + B dequant, g=0) ----
#pragma unroll
    for (int q = 0; q < 4; ++q) async16(gsrcA[q], lds + ldstA[q]);
#pragma unroll
    for (int q = 0; q < 4; ++q) gsrcA[q] += BK;
    {
        uint4 q0 = *(const uint4*)qwp;
        float4 s0 = *(const float4*)szp;
        float4 z0 = *(const float4*)(szp + 4);
        qwp += 8 * N_DIM;                            // -> tile 1
        DQ_WRITE(q0, s0, z0, 0);
    }

    // ---- compute-side ds_read bases (swizzled cols; row&7 == l16&7) ----
    const int h3  = l16 & 7;
    const int cc0 = (quad ^ h3) << 3;          // ks0 col (elements)
    const int cc1 = ((quad ^ h3) ^ 4) << 3;    // ks1 col = cc0 XOR 32 elems
    const int arow = (wm << 7) + l16;          // + mf*16 via imm offset
    const int brow = (wn << 6) + l16;          // + nf*16 via imm offset

    const __bf16* a00 = lds + arow * 64 + cc0;          // buf0 A ks0
    const __bf16* a01 = lds + arow * 64 + cc1;          // buf0 A ks1
    const __bf16* b00 = lds + 32768 + brow * 64 + cc0;  // buf0 B ks0
    const __bf16* b01 = lds + 32768 + brow * 64 + cc1;  // buf0 B ks1

    // 64 K-tiles: tile t computes buf[t&1], stages tile t+1 into the other.
    // Staged-tile scale groups: 2gg+1 -> g=gg (first kgroup, then ADV),
    // 2gg+2 -> g=gg+1 (second kgroup).
#pragma unroll 1
    for (int gg = 0; gg < 31; ++gg) {
        kgroup<true, true >(a00,         a01,         b00,         b01,
                            gsrcA, lds, ldstA, qwp, szp, 16384, acc);
        kgroup<true, false>(a00 + 16384, a01 + 16384, b00 + 16384, b01 + 16384,
                            gsrcA, lds, ldstA, qwp, szp, 0,     acc);
    }
    kgroup<true,  false>(a00,         a01,         b00,         b01,
                         gsrcA, lds, ldstA, qwp, szp, 16384, acc);  // t=62, stages 63 (g=31)
    kgroup<false, false>(a00 + 16384, a01 + 16384, b00 + 16384, b01 + 16384,
                         gsrcA, lds, ldstA, qwp, szp, 0,     acc);  // t=63

    // ---- epilogue: C[m][n] = acc + bias[n]; C/D: col=l16, row=quad*4+r ----
#pragma unroll
    for (int nf = 0; nf < 4; ++nf) {
        const int n = n0 + (wn << 6) + (nf << 4) + l16;
        const float bv = bias[n];
#pragma unroll
        for (int mf = 0; mf < 8; ++mf) {
            const int mrow = m0 + (wm << 7) + (mf << 4) + (quad << 2);
            float* cp = C + (size_t)mrow * N_DIM + n;
#pragma unroll
            for (int r = 0; r < 4; ++r)
                cp[(size_t)r * N_DIM] = acc[mf][nf][r] + bv;
        }
    }
}

// ---------------------------------------------------------------------------
extern "C" void kernel_launch(void* const* d_in, const int* in_sizes, int n_in,
                              void* d_out, int out_size, void* d_ws, size_t ws_size,
                              hipStream_t stream) {
    const float*    x      = (const float*)d_in[0];
    const uint32_t* qwv    = (const uint32_t*)d_in[1];
    const float*    scales = (const float*)d_in[2];
    const float*    zeros  = (const float*)d_in[3];
    const float*    bias   = (const float*)d_in[4];
    float*          out    = (float*)d_out;

    // workspace: xb (M*K bf16 = 33,554,432 B) | szT (32*2752*8*4 = 2,818,048 B)
    __bf16* xb  = (__bf16*)d_ws;
    float*  szT = (float*)((char*)d_ws + (size_t)M_DIM * K_DIM * sizeof(__bf16));

    szt_kernel<<<dim3(N_DIM / 256, GROUPS), 256, 0, stream>>>(scales, zeros, szT);
    xconv_kernel<<<(M_DIM * K_DIM) / (256 * 8), 256, 0, stream>>>(x, xb);
    gemm_kernel<<<NWG, 512, 0, stream>>>(xb, qwv, szT, bias, out);
}

// Round 8
// 591.650 us; speedup vs baseline: 1.0990x; 1.0990x over previous
//
#include <hip/hip_runtime.h>
#include <hip/hip_bf16.h>
#include <cstdint>
#include <cstddef>

// Problem constants
#define K_DIM   4096          // INF
#define N_DIM   11008         // OUTF
#define M_DIM   4096          // 2*2048
#define GROUPS  32
#define QROWS   512           // INF*4/32

typedef __bf16 bf16x8 __attribute__((ext_vector_type(8)));
typedef float  f32x4  __attribute__((ext_vector_type(4)));

// ---------------------------------------------------------------------------
// async 16B global -> LDS (wave-uniform LDS base + lane*16 semantics)
// ---------------------------------------------------------------------------
__device__ __forceinline__ void async16(const void* g, void* lds) {
    __builtin_amdgcn_global_load_lds(
        (const __attribute__((address_space(1))) uint32_t*)g,
        (__attribute__((address_space(3))) uint32_t*)lds,
        16, 0, 0);
}

#define FENCE() asm volatile("" ::: "memory")
#define BAR()   do { FENCE(); __builtin_amdgcn_s_barrier(); FENCE(); } while (0)

// ---------------------------------------------------------------------------
// Kernel 1: dequantize packed 4-bit weights into B^T bf16 layout (N x K).
// (split pipeline restored — R7 fusion put dequant VALU on the critical
// path: +66us VALU-busy unhidden at 2 waves/SIMD lockstep)
// ---------------------------------------------------------------------------
#define DQ_NN   64
#define DQ_KK   32
#define DQ_ROW  264   // 256 k-elements + 8 pad (16B) -> 528B row stride
__global__ __launch_bounds__(256) void dequant_kernel(
        const uint32_t* __restrict__ qw,
        const float* __restrict__ scales,
        const float* __restrict__ zeros,
        __bf16* __restrict__ Wt) {
    __shared__ __align__(16) __bf16 T[DQ_NN * DQ_ROW];   // 33,792 B

    const int n0  = blockIdx.x * DQ_NN;
    const int kk0 = blockIdx.y * DQ_KK;
    const int tid = threadIdx.x;

#pragma unroll
    for (int it = 0; it < 8; ++it) {
        const int flat = it * 256 + tid;
        const int kk_l = flat >> 6;          // 0..31
        const int n_l  = flat & 63;          // 0..63
        const int kk   = kk0 + kk_l;
        const int n    = n0 + n_l;
        const uint32_t q = qw[(size_t)kk * N_DIM + n];
        const int g = kk >> 4;               // k-group = (kk*8)/128
        const float s = scales[(size_t)n * GROUPS + g];
        const float z = zeros[(size_t)n * GROUPS + g];
        bf16x8 w;
#pragma unroll
        for (int j = 0; j < 8; ++j) {
            float v = (float)((q >> (4 * j)) & 0xF) * s - z;
            w[j] = (__bf16)v;
        }
        *(bf16x8*)(&T[n_l * DQ_ROW + kk_l * 8]) = w;
    }
    __syncthreads();

#pragma unroll
    for (int it = 0; it < 8; ++it) {
        const int flat = it * 256 + tid;
        const int n_l    = flat >> 5;        // 0..63
        const int kchunk = flat & 31;        // 0..31 (8 elems each)
        bf16x8 v = *(const bf16x8*)(&T[n_l * DQ_ROW + kchunk * 8]);
        *(bf16x8*)(Wt + (size_t)(n0 + n_l) * K_DIM + (size_t)kk0 * 8 + kchunk * 8) = v;
    }
}

// ---------------------------------------------------------------------------
// Kernel 2: x fp32 -> bf16 (RNE), 8 elements per thread (unchanged)
// ---------------------------------------------------------------------------
__global__ __launch_bounds__(256) void xconv_kernel(
        const float* __restrict__ x, __bf16* __restrict__ xb) {
    const size_t i = ((size_t)blockIdx.x * 256 + threadIdx.x) * 8;
    const float4* p = (const float4*)(x + i);
    float4 a = p[0];
    float4 b = p[1];
    bf16x8 o;
    o[0] = (__bf16)a.x; o[1] = (__bf16)a.y; o[2] = (__bf16)a.z; o[3] = (__bf16)a.w;
    o[4] = (__bf16)b.x; o[5] = (__bf16)b.y; o[6] = (__bf16)b.z; o[7] = (__bf16)b.w;
    *(bf16x8*)(xb + i) = o;
}

// ---------------------------------------------------------------------------
// Kernel 3: bf16 GEMM, C = A(M x K) * Bt(N x K)^T + bias, fp32 out.
//
// 256x256 tile, BK=64, 512 threads = 8 waves (2M x 4N), acc[8][4] f32x4.
// XOR-8 LDS swizzle via pre-swizzled global source (rule 21); bijective
// XCD block swizzle.
//
// R8 change (T4 on the R4 structure): counted vmcnt, never 0 in the loop.
//   Staging split (unchanged from R4): p0 issues {Aq0,Aq2,Bq0,Bq1},
//   post-mid issues {Bq2,Bq3,Aq1,Aq3}.
//   seam: vmcnt(2)+BAR  -> certifies+publishes cur {Aq0,Aq2,B*} (exactly
//         what p0/p2 read); cur {Aq1,Aq3} stay in flight.  All 6 waited
//         loads are ~1 K-tile old (~1250cyc > HBM latency) -> no stall,
//         vs R4's vmcnt(0) draining 0.5-tile-young loads (~300cyc stall).
//   mid:  vmcnt(4)+BAR  -> certifies+publishes cur {Aq1,Aq3} (queue =
//         cur2 + next-p0 4); needed by p1/p3 A-reads.  Also ~1 tile old.
//   vmcnt is per-wave and every staging quarter is written by all 8 waves,
//   so each counted wait is followed by a barrier to publish cross-wave.
// Phases: p0 ks0·mf0-3 | mid | p1 ks0·mf4-7 | p2 ks1·mf0-3 | p3 ks1·mf4-7.
// Last tile: seam vmcnt(2) (8 outstanding -> waits 6), mid vmcnt(0).
// ---------------------------------------------------------------------------
#define BM 256
#define BN 256
#define BK 64
#define NT 43            // N_DIM/256
#define MT 16            // M_DIM/256
#define NWG (NT*MT)      // 688 = 8*86 -> bijective XCD swizzle

#define MFMA4(AV, R)                                                          \
    acc[(R)][0] = __builtin_amdgcn_mfma_f32_16x16x32_bf16((AV), b0, acc[(R)][0], 0,0,0); \
    acc[(R)][1] = __builtin_amdgcn_mfma_f32_16x16x32_bf16((AV), b1, acc[(R)][1], 0,0,0); \
    acc[(R)][2] = __builtin_amdgcn_mfma_f32_16x16x32_bf16((AV), b2, acc[(R)][2], 0,0,0); \
    acc[(R)][3] = __builtin_amdgcn_mfma_f32_16x16x32_bf16((AV), b3, acc[(R)][3], 0,0,0);

// One K-tile: 4 ks-major phases, 2 barriers (seam + mid), counted vmcnt.
template<bool DO_STAGE>
__device__ __forceinline__ void kgroup(
        const __bf16* __restrict__ ar0, const __bf16* __restrict__ ar1,
        const __bf16* __restrict__ br0, const __bf16* __restrict__ br1,
        const __bf16* (&gsrc)[8], __bf16* lds, const int (&ldst)[8],
        const int soff, f32x4 (&acc)[8][4])
{
    bf16x8 a0, a1, a2, a3, b0, b1, b2, b3;

    // ---- seam: certify cur {Aq0,Aq2,B*} (oldest 6), publish cross-wave ----
    asm volatile("s_waitcnt vmcnt(2)" ::: "memory");
    BAR();

    // ---- p0 : ks0, mf0-3 ; issue next-tile {Aq0,Aq2,Bq0,Bq1} ----
    if constexpr (DO_STAGE) {
        async16(gsrc[0], lds + ldst[0] + soff);
        async16(gsrc[1], lds + ldst[1] + soff);
        async16(gsrc[2], lds + ldst[2] + soff);
        async16(gsrc[3], lds + ldst[3] + soff);
    }
    a0 = *(const bf16x8*)(ar0 + 0*1024);
    a1 = *(const bf16x8*)(ar0 + 1*1024);
    a2 = *(const bf16x8*)(ar0 + 2*1024);
    a3 = *(const bf16x8*)(ar0 + 3*1024);
    b0 = *(const bf16x8*)(br0 + 0*1024);
    b1 = *(const bf16x8*)(br0 + 1*1024);
    b2 = *(const bf16x8*)(br0 + 2*1024);
    b3 = *(const bf16x8*)(br0 + 3*1024);
    __builtin_amdgcn_s_setprio(1);
    MFMA4(a0, 0) MFMA4(a1, 1) MFMA4(a2, 2) MFMA4(a3, 3)
    __builtin_amdgcn_s_setprio(0);

    // ---- mid: certify cur {Aq1,Aq3} (queue = cur2 + next4), publish ----
    if constexpr (DO_STAGE) { asm volatile("s_waitcnt vmcnt(4)" ::: "memory"); }
    else                    { asm volatile("s_waitcnt vmcnt(0)" ::: "memory"); }
    BAR();

    // ---- p1 : ks0, mf4-7 ; issue next-tile {Bq2,Bq3,Aq1,Aq3} ----
    if constexpr (DO_STAGE) {
        async16(gsrc[4], lds + ldst[4] + soff);
        async16(gsrc[5], lds + ldst[5] + soff);
        async16(gsrc[6], lds + ldst[6] + soff);
        async16(gsrc[7], lds + ldst[7] + soff);
    }
    a0 = *(const bf16x8*)(ar0 + 4*1024);
    a1 = *(const bf16x8*)(ar0 + 5*1024);
    a2 = *(const bf16x8*)(ar0 + 6*1024);
    a3 = *(const bf16x8*)(ar0 + 7*1024);
    __builtin_amdgcn_s_setprio(1);
    MFMA4(a0, 4) MFMA4(a1, 5) MFMA4(a2, 6) MFMA4(a3, 7)
    __builtin_amdgcn_s_setprio(0);

    // ---- p2 : ks1, mf0-3 (A q0/q2, B: certified at seam) ----
    a0 = *(const bf16x8*)(ar1 + 0*1024);
    a1 = *(const bf16x8*)(ar1 + 1*1024);
    a2 = *(const bf16x8*)(ar1 + 2*1024);
    a3 = *(const bf16x8*)(ar1 + 3*1024);
    b0 = *(const bf16x8*)(br1 + 0*1024);
    b1 = *(const bf16x8*)(br1 + 1*1024);
    b2 = *(const bf16x8*)(br1 + 2*1024);
    b3 = *(const bf16x8*)(br1 + 3*1024);
    __builtin_amdgcn_s_setprio(1);
    MFMA4(a0, 0) MFMA4(a1, 1) MFMA4(a2, 2) MFMA4(a3, 3)
    __builtin_amdgcn_s_setprio(0);

    // ---- p3 : ks1, mf4-7 (A q1/q3: certified at mid) ----
    a0 = *(const bf16x8*)(ar1 + 4*1024);
    a1 = *(const bf16x8*)(ar1 + 5*1024);
    a2 = *(const bf16x8*)(ar1 + 6*1024);
    a3 = *(const bf16x8*)(ar1 + 7*1024);
    __builtin_amdgcn_s_setprio(1);
    MFMA4(a0, 4) MFMA4(a1, 5) MFMA4(a2, 6) MFMA4(a3, 7)
    __builtin_amdgcn_s_setprio(0);

    if constexpr (DO_STAGE) {
#pragma unroll
        for (int j = 0; j < 8; ++j) gsrc[j] += BK;
    }
}

__global__ __launch_bounds__(512, 2) void gemm_kernel(
        const __bf16* __restrict__ A,    // M x K row-major (bf16 x)
        const __bf16* __restrict__ Bt,   // N x K row-major (dequant W^T)
        const float* __restrict__ bias,  // N
        float* __restrict__ C) {         // M x N row-major
    __shared__ __align__(16) __bf16 lds[65536];   // 128 KiB

    const int tid  = threadIdx.x;
    const int wave = tid >> 6;
    const int lane = tid & 63;
    const int wm   = wave >> 2;      // 0..1
    const int wn   = wave & 3;       // 0..3
    const int quad = lane >> 4;      // 0..3
    const int l16  = lane & 15;

    // bijective XCD swizzle (688 % 8 == 0), m inner for B-panel L2 reuse
    const int bid = blockIdx.x;
    const int swz = (bid & 7) * (NWG / 8) + (bid >> 3);
    const int n_t = swz >> 4;        // 0..42
    const int m_t = swz & 15;        // 0..15
    const int m0 = m_t << 8;
    const int n0 = n_t << 8;

    f32x4 acc[8][4] = {};

    // ---- staging source (pre-swizzled global addresses, rule 21) ----
    const int srow = tid >> 3;                       // 0..63 row within quarter
    const int scol = ((tid & 7) ^ (srow & 7)) << 3;  // swizzled k-chunk * 8

    // issue order: p0: Aq0, Aq2, Bq0, Bq1 | post-mid: Bq2, Bq3, Aq1, Aq3
    const __bf16* gsrc[8];
    gsrc[0] = A  + (size_t)(m0 +   0 + srow) * K_DIM + scol;
    gsrc[1] = A  + (size_t)(m0 + 128 + srow) * K_DIM + scol;
    gsrc[2] = Bt + (size_t)(n0 +   0 + srow) * K_DIM + scol;
    gsrc[3] = Bt + (size_t)(n0 +  64 + srow) * K_DIM + scol;
    gsrc[4] = Bt + (size_t)(n0 + 128 + srow) * K_DIM + scol;
    gsrc[5] = Bt + (size_t)(n0 + 192 + srow) * K_DIM + scol;
    gsrc[6] = A  + (size_t)(m0 +  64 + srow) * K_DIM + scol;
    gsrc[7] = A  + (size_t)(m0 + 192 + srow) * K_DIM + scol;

    // wave-uniform LDS dest (elements): quarter base + wave*512 (HW adds lane*16B)
    const int wq = wave << 9;
    const int ldst[8] = {
        0*4096 + wq,          2*4096 + wq,
        32768 + 0*4096 + wq,  32768 + 1*4096 + wq,
        32768 + 2*4096 + wq,  32768 + 3*4096 + wq,
        1*4096 + wq,          3*4096 + wq
    };

    // prologue: tile 0 -> buf0 (same 8-deep queue as steady state)
#pragma unroll
    for (int j = 0; j < 8; ++j) async16(gsrc[j], lds + ldst[j]);
#pragma unroll
    for (int j = 0; j < 8; ++j) gsrc[j] += BK;

    // ---- compute-side ds_read bases (swizzled cols; row&7 == l16&7) ----
    const int h3  = l16 & 7;
    const int cc0 = (quad ^ h3) << 3;          // ks0 col (elements)
    const int cc1 = ((quad ^ h3) ^ 4) << 3;    // ks1 col = cc0 XOR 32 elems
    const int arow = (wm << 7) + l16;          // + mf*16 via imm offset
    const int brow = (wn << 6) + l16;          // + nf*16 via imm offset

    const __bf16* a00 = lds + arow * 64 + cc0;          // buf0 A ks0
    const __bf16* a01 = lds + arow * 64 + cc1;          // buf0 A ks1
    const __bf16* b00 = lds + 32768 + brow * 64 + cc0;  // buf0 B ks0
    const __bf16* b01 = lds + 32768 + brow * 64 + cc1;  // buf0 B ks1

    // 64 K-tiles: groups alternate buf0/buf1; group g stages tile g+1.
#pragma unroll 1
    for (int gg = 0; gg < 31; ++gg) {
        kgroup<true>(a00,         a01,         b00,         b01,
                     gsrc, lds, ldst, 16384, acc);
        kgroup<true>(a00 + 16384, a01 + 16384, b00 + 16384, b01 + 16384,
                     gsrc, lds, ldst, 0,     acc);
    }
    kgroup<true >(a00,         a01,         b00,         b01,
                  gsrc, lds, ldst, 16384, acc);   // g=62 stages tile 63
    kgroup<false>(a00 + 16384, a01 + 16384, b00 + 16384, b01 + 16384,
                  gsrc, lds, ldst, 0,     acc);   // g=63, drain 2->0

    // ---- epilogue: C[m][n] = acc + bias[n]; C/D: col=l16, row=quad*4+r ----
#pragma unroll
    for (int nf = 0; nf < 4; ++nf) {
        const int n = n0 + (wn << 6) + (nf << 4) + l16;
        const float bv = bias[n];
#pragma unroll
        for (int mf = 0; mf < 8; ++mf) {
            const int mrow = m0 + (wm << 7) + (mf << 4) + (quad << 2);
            float* cp = C + (size_t)mrow * N_DIM + n;
#pragma unroll
            for (int r = 0; r < 4; ++r)
                cp[(size_t)r * N_DIM] = acc[mf][nf][r] + bv;
        }
    }
}

// ---------------------------------------------------------------------------
extern "C" void kernel_launch(void* const* d_in, const int* in_sizes, int n_in,
                              void* d_out, int out_size, void* d_ws, size_t ws_size,
                              hipStream_t stream) {
    const float*    x      = (const float*)d_in[0];
    const uint32_t* qw     = (const uint32_t*)d_in[1];
    const float*    scales = (const float*)d_in[2];
    const float*    zeros  = (const float*)d_in[3];
    const float*    bias   = (const float*)d_in[4];
    float*          out    = (float*)d_out;

    // workspace layout: Wt (N*K bf16 = 90,177,536 B) | xb (M*K bf16 = 33,554,432 B)
    __bf16* Wt = (__bf16*)d_ws;
    __bf16* xb = (__bf16*)((char*)d_ws + (size_t)N_DIM * K_DIM * sizeof(__bf16));

    dim3 dq_grid(N_DIM / DQ_NN, QROWS / DQ_KK);   // 172 x 16
    dequant_kernel<<<dq_grid, 256, 0, stream>>>(qw, scales, zeros, Wt);
    xconv_kernel<<<(M_DIM * K_DIM) / (256 * 8), 256, 0, stream>>>(x, xb);

    gemm_kernel<<<NWG, 512, 0, stream>>>(xb, Wt, bias, out);
}